// Round 5
// baseline (168.750 us; speedup 1.0000x reference)
//
#include <hip/hip_runtime.h>

#define HF 400
#define WF 400
#define NB 8
#define ND 96
#define NH 192
#define NW 192
#define TH 8   // h-values per thread

// Batch moved to grid.z: each thread does only 2 gather loads + 1 store per
// h-iter (x/y math duplicated across b -- VALU is nearly idle, this is free).
// 8x more waves than R3 to cover L2 gather latency; each block writes one
// dense contiguous out region; co-resident blocks share one hot image in L2.
__global__ __launch_bounds__(NW) void fluence_vol_kernel(
    const float* __restrict__ fluence,   // [B, HF, WF]
    const float* __restrict__ grids,     // [D, W, H, 2]
    const float* __restrict__ pc,        // [D]
    float* __restrict__ out)             // [B, D, H, W]
{
    const int w  = threadIdx.x;
    const int h0 = blockIdx.x * TH;
    const int d  = blockIdx.y;
    const int b  = blockIdx.z;

    // ---- per-thread x path (once per TH outputs) ----
    const float x = grids[(d * NW + w) * NH * 2];
    const float ix = ((x + 1.0f) * WF - 1.0f) * 0.5f;
    const float ix0f = floorf(ix);
    const int ix0 = (int)ix0f;
    const int ix1 = ix0 + 1;
    const float wx1 = ix - ix0f;
    const float wx0 = 1.0f - wx1;
    const int cx0 = min(max(ix0, 0), WF - 1);
    const int cx1 = min(max(ix1, 0), WF - 1);
    const int xb  = min(max(ix0, 0), WF - 2);   // pair window [xb, xb+1]
    const float wxv0 = ((ix0 >= 0) && (ix0 < WF)) ? wx0 : 0.0f;
    const float wxv1 = ((ix1 >= 0) && (ix1 < WF)) ? wx1 : 0.0f;
    const float ax = ((cx0 == xb)     ? wxv0 : 0.0f) + ((cx1 == xb)     ? wxv1 : 0.0f);
    const float bx = ((cx0 == xb + 1) ? wxv0 : 0.0f) + ((cx1 == xb + 1) ? wxv1 : 0.0f);

    const float corr = pc[d];
    const float* __restrict__ gy  = grids + (d * NW * NH) * 2 + 1;
    const float* __restrict__ img = fluence + b * (HF * WF);
    float* __restrict__ op = out + ((size_t)(b * ND + d) * NH + h0) * NW + w;

#pragma unroll
    for (int hh = 0; hh < TH; ++hh) {
        // ---- y path (uniform across the wave) ----
        const float y = gy[(h0 + hh) * 2];
        const float iy = ((y + 1.0f) * HF - 1.0f) * 0.5f;
        const float iy0f = floorf(iy);
        const int iy0 = (int)iy0f;
        const int iy1 = iy0 + 1;
        const float wy1 = iy - iy0f;
        const float wy0 = 1.0f - wy1;
        const int cy0 = min(max(iy0, 0), HF - 1);
        const int cy1 = min(max(iy1, 0), HF - 1);
        const float wyc0 = (((iy0 >= 0) && (iy0 < HF)) ? wy0 : 0.0f) * corr;
        const float wyc1 = (((iy1 >= 0) && (iy1 < HF)) ? wy1 : 0.0f) * corr;

        const float2 p0 = *(const float2*)(img + cy0 * WF + xb);
        const float2 p1 = *(const float2*)(img + cy1 * WF + xb);

        const float v0 = fmaf(p0.y, bx, p0.x * ax);
        const float v1 = fmaf(p1.y, bx, p1.x * ax);
        __builtin_nontemporal_store(fmaf(v1, wyc1, v0 * wyc0), op + hh * NW);
    }
}

extern "C" void kernel_launch(void* const* d_in, const int* in_sizes, int n_in,
                              void* d_out, int out_size, void* d_ws, size_t ws_size,
                              hipStream_t stream) {
    const float* fluence = (const float*)d_in[0];  // [8, 400, 400]
    const float* grids   = (const float*)d_in[1];  // [96, 192, 192, 2]
    const float* pc      = (const float*)d_in[2];  // [96]
    float* out = (float*)d_out;                    // [8, 96, 192, 192]

    dim3 grid(NH / TH, ND, NB);   // (h-tile, d, b)
    dim3 block(NW);               // w
    fluence_vol_kernel<<<grid, block, 0, stream>>>(fluence, grids, pc, out);
}